// Round 1
// baseline (3357.939 us; speedup 1.0000x reference)
//
#include <hip/hip_runtime.h>
#include <math.h>

#define NPTS 4096
#define NB 16
#define NS 1024
#define KNB 32
#define CPTS 64

// ws float layout
#define WT0_OFF 0        // 67*64 transposed w0 [c][o]
#define WT1_OFF 4288     // 64*64
#define WT2_OFF 8384     // 64*128
#define PRM_OFF 16576    // A0(64) B0(64) A1(64) B1(64) A2(128) B2(128)
#define WS_FLOATS 17088

// ---------------- setup: transpose weights, fold BN ----------------
__global__ __launch_bounds__(256) void setup_kernel(
    const float* __restrict__ w0, const float* __restrict__ cb0, const float* __restrict__ g0,
    const float* __restrict__ b0, const float* __restrict__ m0, const float* __restrict__ v0,
    const float* __restrict__ w1, const float* __restrict__ cb1, const float* __restrict__ g1,
    const float* __restrict__ b1, const float* __restrict__ m1, const float* __restrict__ v1,
    const float* __restrict__ w2, const float* __restrict__ cb2, const float* __restrict__ g2,
    const float* __restrict__ b2, const float* __restrict__ m2, const float* __restrict__ v2,
    float* __restrict__ ws) {
  int i = blockIdx.x * 256 + threadIdx.x;
  if (i >= WS_FLOATS) return;
  if (i < WT1_OFF) {                       // wT0[c][o] = w0[o][c], w0 is [64][67]
    int c = i >> 6, o = i & 63;
    ws[i] = w0[o * 67 + c];
  } else if (i < WT2_OFF) {                // wT1, w1 is [64][64]
    int k = i - WT1_OFF; int c = k >> 6, o = k & 63;
    ws[i] = w1[o * 64 + c];
  } else if (i < PRM_OFF) {                // wT2[c][o], w2 is [128][64]
    int k = i - WT2_OFF; int c = k >> 7, o = k & 127;
    ws[i] = w2[o * 64 + c];
  } else {
    int k = i - PRM_OFF;
    if (k < 64)        { ws[i] = g0[k] / sqrtf(v0[k] + 1e-5f); }
    else if (k < 128)  { int o = k - 64;  float sc = g0[o] / sqrtf(v0[o] + 1e-5f);
                         ws[i] = (cb0[o] - m0[o]) * sc + b0[o]; }
    else if (k < 192)  { int o = k - 128; ws[i] = g1[o] / sqrtf(v1[o] + 1e-5f); }
    else if (k < 256)  { int o = k - 192; float sc = g1[o] / sqrtf(v1[o] + 1e-5f);
                         ws[i] = (cb1[o] - m1[o]) * sc + b1[o]; }
    else if (k < 384)  { int o = k - 256; ws[i] = g2[o] / sqrtf(v2[o] + 1e-5f); }
    else               { int o = k - 384; float sc = g2[o] / sqrtf(v2[o] + 1e-5f);
                         ws[i] = (cb2[o] - m2[o]) * sc + b2[o]; }
  }
}

// ---------------- FPS: one block per batch, bit-exact vs reference ----------------
__global__ __launch_bounds__(512) void fps_kernel(const float* __restrict__ xyz,
                                                  float* __restrict__ newxyz) {
  const int b = blockIdx.x;
  const int t = threadIdx.x;
  const float* xb = xyz + (size_t)b * NPTS * 3;
  float* outb = newxyz + (size_t)b * NS * 3;

  __shared__ float sxyz[NPTS * 3];
  __shared__ float cent[3];
  __shared__ float pv[8];
  __shared__ int   pi[8];

  for (int i = t; i < NPTS * 3; i += 512) sxyz[i] = xb[i];

  float px[8], py[8], pz[8], dist[8];
#pragma unroll
  for (int j = 0; j < 8; ++j) {
    int n = t + 512 * j;
    px[j] = xb[n * 3 + 0];
    py[j] = xb[n * 3 + 1];
    pz[j] = xb[n * 3 + 2];
    dist[j] = 1e10f;
  }
  __syncthreads();
  if (t == 0) {
    cent[0] = sxyz[0]; cent[1] = sxyz[1]; cent[2] = sxyz[2];
    outb[0] = sxyz[0]; outb[1] = sxyz[1]; outb[2] = sxyz[2];
  }
  __syncthreads();

  for (int it = 1; it < NS; ++it) {
    float cx = cent[0], cy = cent[1], cz = cent[2];
    float best = -1.0f; int bidx = 0;
#pragma unroll
    for (int j = 0; j < 8; ++j) {
      // exact replication of sum((xyz - c)**2, -1): no FMA contraction
      float dx = __fsub_rn(px[j], cx);
      float dy = __fsub_rn(py[j], cy);
      float dz = __fsub_rn(pz[j], cz);
      float d  = __fadd_rn(__fadd_rn(__fmul_rn(dx, dx), __fmul_rn(dy, dy)), __fmul_rn(dz, dz));
      float dm = fminf(dist[j], d);
      dist[j] = dm;
      if (dm > best) { best = dm; bidx = t + 512 * j; }   // ascending idx: first-max kept
    }
    // wave all-reduce: lexicographic max on (value, -idx) — assoc+comm
#pragma unroll
    for (int off = 32; off >= 1; off >>= 1) {
      float ov = __shfl_xor(best, off, 64);
      int   oi = __shfl_xor(bidx, off, 64);
      if (ov > best || (ov == best && oi < bidx)) { best = ov; bidx = oi; }
    }
    if ((t & 63) == 0) { pv[t >> 6] = best; pi[t >> 6] = bidx; }
    __syncthreads();
    if (t == 0) {
      float bv = pv[0]; int bi = pi[0];
#pragma unroll
      for (int w = 1; w < 8; ++w)
        if (pv[w] > bv || (pv[w] == bv && pi[w] < bi)) { bv = pv[w]; bi = pi[w]; }
      float nx = sxyz[bi * 3], ny = sxyz[bi * 3 + 1], nz = sxyz[bi * 3 + 2];
      cent[0] = nx; cent[1] = ny; cent[2] = nz;
      outb[it * 3 + 0] = nx; outb[it * 3 + 1] = ny; outb[it * 3 + 2] = nz;
    }
    __syncthreads();
  }
}

// ---------------- MLP layer: X[32][Cin](LDS) x wT[Cin][Cout](global) -> Y[32][Cout](LDS)
template <int CIN, int COUT, int XSTR, int YSTR>
__device__ __forceinline__ void mlp_layer(const float* Xb, const float* __restrict__ wT,
                                          const float* __restrict__ Aa, const float* __restrict__ Bb,
                                          float* Yb, int t) {
  constexpr int NJ = COUT / 8;
  const int og = t & 7, kk = t >> 3;
  const int obase = og * NJ;
  float acc[NJ];
#pragma unroll
  for (int j = 0; j < NJ; ++j) acc[j] = 0.f;
  const float* xrow = Xb + kk * XSTR;
  for (int c = 0; c < CIN; ++c) {
    float xv = xrow[c];
    const float* wr = wT + c * COUT + obase;
#pragma unroll
    for (int j = 0; j < NJ; ++j) acc[j] = fmaf(xv, wr[j], acc[j]);
  }
#pragma unroll
  for (int j = 0; j < NJ; ++j) {
    int o = obase + j;
    Yb[kk * YSTR + o] = fmaxf(fmaf(acc[j], Aa[o], Bb[o]), 0.f);  // BN(eval) + ReLU
  }
}

// ---------------- fused 32-NN + gather + MLP + maxpool: one block per (b,s) ----------------
__global__ __launch_bounds__(256) void knnmlp_kernel(
    const float* __restrict__ xyz, const float* __restrict__ points,
    const float* __restrict__ ws, const float* __restrict__ newxyz,
    float* __restrict__ outp) {
  const int blk = blockIdx.x;
  const int b = blk >> 10, s = blk & 1023;
  const int t = threadIdx.x;
  const float* xb = xyz + (size_t)b * NPTS * 3;
  const float* pb = points + (size_t)b * NPTS * CPTS;
  const float* q  = newxyz + ((size_t)b * NS + s) * 3;
  float qx = q[0], qy = q[1], qz = q[2];
  // exact replication of (s2 - 2*dot) + n2
  float s2 = __fadd_rn(__fadd_rn(__fmul_rn(qx, qx), __fmul_rn(qy, qy)), __fmul_rn(qz, qz));
  float d[16];
#pragma unroll
  for (int j = 0; j < 16; ++j) {
    int n = t + 256 * j;
    float px = xb[n * 3], py = xb[n * 3 + 1], pz = xb[n * 3 + 2];
    float n2 = __fadd_rn(__fadd_rn(__fmul_rn(px, px), __fmul_rn(py, py)), __fmul_rn(pz, pz));
    float dt = __fadd_rn(__fadd_rn(__fmul_rn(qx, px), __fmul_rn(qy, py)), __fmul_rn(qz, pz));
    d[j] = __fadd_rn(__fsub_rn(s2, __fmul_rn(2.0f, dt)), n2);
  }

  __shared__ float pv[4]; __shared__ int pi[4];
  __shared__ int   nn[KNB];
  __shared__ float s_lv; __shared__ int s_li;

  // 32 rounds of argmin over (d, idx) lexicographic, restricted to > last selected.
  float lv = -3.0e38f; int li = -1;
  for (int r = 0; r < KNB; ++r) {
    float bv = 3.0e38f; int bi = 0x7fffffff;
#pragma unroll
    for (int j = 0; j < 16; ++j) {
      int idx = t + 256 * j;
      bool valid  = (d[j] > lv) || (d[j] == lv && idx > li);
      bool better = (d[j] < bv) || (d[j] == bv && idx < bi);
      if (valid && better) { bv = d[j]; bi = idx; }
    }
#pragma unroll
    for (int off = 32; off >= 1; off >>= 1) {
      float ov = __shfl_xor(bv, off, 64);
      int   oi = __shfl_xor(bi, off, 64);
      if (ov < bv || (ov == bv && oi < bi)) { bv = ov; bi = oi; }
    }
    if ((t & 63) == 0) { pv[t >> 6] = bv; pi[t >> 6] = bi; }
    __syncthreads();
    if (t == 0) {
      float mv = pv[0]; int mi = pi[0];
#pragma unroll
      for (int w = 1; w < 4; ++w)
        if (pv[w] < mv || (pv[w] == mv && pi[w] < mi)) { mv = pv[w]; mi = pi[w]; }
      nn[r] = mi; s_lv = mv; s_li = mi;
    }
    __syncthreads();
    lv = s_lv; li = s_li;
  }

  __shared__ float X[32][68];
  __shared__ float P[32][68];
  __shared__ float O2[32][132];

  // gather grouped features: [32][3 xyz-norm | 64 point feats]
  for (int e = t; e < 32 * 67; e += 256) {
    int k = e / 67, c = e - k * 67;
    int idx = nn[k];
    float v;
    if (c < 3) {
      float qc = (c == 0) ? qx : ((c == 1) ? qy : qz);
      v = __fsub_rn(xb[idx * 3 + c], qc);
    } else {
      v = pb[idx * CPTS + (c - 3)];
    }
    X[k][c] = v;
  }
  __syncthreads();

  mlp_layer<67, 64, 68, 68>(&X[0][0], ws + WT0_OFF, ws + PRM_OFF, ws + PRM_OFF + 64, &P[0][0], t);
  __syncthreads();
  mlp_layer<64, 64, 68, 68>(&P[0][0], ws + WT1_OFF, ws + PRM_OFF + 128, ws + PRM_OFF + 192, &X[0][0], t);
  __syncthreads();
  mlp_layer<64, 128, 68, 132>(&X[0][0], ws + WT2_OFF, ws + PRM_OFF + 256, ws + PRM_OFF + 384, &O2[0][0], t);
  __syncthreads();

  if (t < 128) {
    float m = O2[0][t];
#pragma unroll
    for (int k2 = 1; k2 < 32; ++k2) m = fmaxf(m, O2[k2][t]);
    outp[((size_t)b * 128 + t) * NS + s] = m;
  }
}

extern "C" void kernel_launch(void* const* d_in, const int* in_sizes, int n_in,
                              void* d_out, int out_size, void* d_ws, size_t ws_size,
                              hipStream_t stream) {
  const float* xyz    = (const float*)d_in[0];
  const float* points = (const float*)d_in[1];
  const float* w0  = (const float*)d_in[2];
  const float* cb0 = (const float*)d_in[3];
  const float* g0  = (const float*)d_in[4];
  const float* b0  = (const float*)d_in[5];
  const float* m0  = (const float*)d_in[6];
  const float* v0  = (const float*)d_in[7];
  const float* w1  = (const float*)d_in[8];
  const float* cb1 = (const float*)d_in[9];
  const float* g1  = (const float*)d_in[10];
  const float* b1  = (const float*)d_in[11];
  const float* m1  = (const float*)d_in[12];
  const float* v1  = (const float*)d_in[13];
  const float* w2  = (const float*)d_in[14];
  const float* cb2 = (const float*)d_in[15];
  const float* g2  = (const float*)d_in[16];
  const float* b2  = (const float*)d_in[17];
  const float* m2  = (const float*)d_in[18];
  const float* v2  = (const float*)d_in[19];

  float* ws     = (float*)d_ws;
  float* newxyz = (float*)d_out;                       // output 0: [16,1024,3]
  float* outp   = (float*)d_out + (size_t)NB * NS * 3; // output 1: [16,128,1024]

  setup_kernel<<<(WS_FLOATS + 255) / 256, 256, 0, stream>>>(
      w0, cb0, g0, b0, m0, v0, w1, cb1, g1, b1, m1, v1, w2, cb2, g2, b2, m2, v2, ws);
  fps_kernel<<<NB, 512, 0, stream>>>(xyz, newxyz);
  knnmlp_kernel<<<NB * NS, 256, 0, stream>>>(xyz, points, ws, newxyz, outp);
}

// Round 2
// 2717.917 us; speedup vs baseline: 1.2355x; 1.2355x over previous
//
#include <hip/hip_runtime.h>
#include <math.h>

#define NPTS 4096
#define NB 16
#define NS 1024
#define KNB 32
#define CPTS 64

// ws float layout
#define WT0_OFF 0        // 67*64 transposed w0 [c][o]
#define WT1_OFF 4288     // 64*64
#define WT2_OFF 8384     // 64*128
#define PRM_OFF 16576    // A0(64) B0(64) A1(64) B1(64) A2(128) B2(128)
#define WS_FLOATS 17088

// ---------------- setup: transpose weights, fold BN ----------------
__global__ __launch_bounds__(256) void setup_kernel(
    const float* __restrict__ w0, const float* __restrict__ cb0, const float* __restrict__ g0,
    const float* __restrict__ b0, const float* __restrict__ m0, const float* __restrict__ v0,
    const float* __restrict__ w1, const float* __restrict__ cb1, const float* __restrict__ g1,
    const float* __restrict__ b1, const float* __restrict__ m1, const float* __restrict__ v1,
    const float* __restrict__ w2, const float* __restrict__ cb2, const float* __restrict__ g2,
    const float* __restrict__ b2, const float* __restrict__ m2, const float* __restrict__ v2,
    float* __restrict__ ws) {
  int i = blockIdx.x * 256 + threadIdx.x;
  if (i >= WS_FLOATS) return;
  if (i < WT1_OFF) {                       // wT0[c][o] = w0[o][c], w0 is [64][67]
    int c = i >> 6, o = i & 63;
    ws[i] = w0[o * 67 + c];
  } else if (i < WT2_OFF) {                // wT1, w1 is [64][64]
    int k = i - WT1_OFF; int c = k >> 6, o = k & 63;
    ws[i] = w1[o * 64 + c];
  } else if (i < PRM_OFF) {                // wT2[c][o], w2 is [128][64]
    int k = i - WT2_OFF; int c = k >> 7, o = k & 127;
    ws[i] = w2[o * 64 + c];
  } else {
    int k = i - PRM_OFF;
    if (k < 64)        { ws[i] = g0[k] / sqrtf(v0[k] + 1e-5f); }
    else if (k < 128)  { int o = k - 64;  float sc = g0[o] / sqrtf(v0[o] + 1e-5f);
                         ws[i] = (cb0[o] - m0[o]) * sc + b0[o]; }
    else if (k < 192)  { int o = k - 128; ws[i] = g1[o] / sqrtf(v1[o] + 1e-5f); }
    else if (k < 256)  { int o = k - 192; float sc = g1[o] / sqrtf(v1[o] + 1e-5f);
                         ws[i] = (cb1[o] - m1[o]) * sc + b1[o]; }
    else if (k < 384)  { int o = k - 256; ws[i] = g2[o] / sqrtf(v2[o] + 1e-5f); }
    else               { int o = k - 384; float sc = g2[o] / sqrtf(v2[o] + 1e-5f);
                         ws[i] = (cb2[o] - m2[o]) * sc + b2[o]; }
  }
}

// ---------------- FPS: one block (256 thr) per batch, ONE barrier/iter, bit-exact ----------------
__global__ __launch_bounds__(256) void fps_kernel(const float* __restrict__ xyz,
                                                  float* __restrict__ newxyz) {
  const int b = blockIdx.x;
  const int t = threadIdx.x;
  const float* xb = xyz + (size_t)b * NPTS * 3;
  float* outb = newxyz + (size_t)b * NS * 3;

  __shared__ float sxyz[NPTS * 3];
  __shared__ float pv[2][4];
  __shared__ int   pi2[2][4];

  for (int i = t; i < NPTS * 3; i += 256) sxyz[i] = xb[i];

  float px[16], py[16], pz[16], dist[16];
#pragma unroll
  for (int j = 0; j < 16; ++j) {
    int n = t + 256 * j;
    px[j] = xb[n * 3 + 0];
    py[j] = xb[n * 3 + 1];
    pz[j] = xb[n * 3 + 2];
    dist[j] = 1e10f;
  }
  __syncthreads();
  float cx = sxyz[0], cy = sxyz[1], cz = sxyz[2];
  if (t == 0) { outb[0] = cx; outb[1] = cy; outb[2] = cz; }

  int buf = 0;
  for (int it = 1; it < NS; ++it) {
    float best = -1.0f; int bidx = 0;
#pragma unroll
    for (int j = 0; j < 16; ++j) {
      // exact replication of sum((xyz - c)**2, -1): no FMA contraction
      float dx = __fsub_rn(px[j], cx);
      float dy = __fsub_rn(py[j], cy);
      float dz = __fsub_rn(pz[j], cz);
      float d  = __fadd_rn(__fadd_rn(__fmul_rn(dx, dx), __fmul_rn(dy, dy)), __fmul_rn(dz, dz));
      float dm = fminf(dist[j], d);
      dist[j] = dm;
      if (dm > best) { best = dm; bidx = t + 256 * j; }  // ascending idx: first-max kept
    }
#pragma unroll
    for (int off = 32; off >= 1; off >>= 1) {
      float ov = __shfl_xor(best, off, 64);
      int   oi = __shfl_xor(bidx, off, 64);
      if (ov > best || (ov == best && oi < bidx)) { best = ov; bidx = oi; }
    }
    if ((t & 63) == 0) { pv[buf][t >> 6] = best; pi2[buf][t >> 6] = bidx; }
    __syncthreads();
    // replicated merge of 4 wave partials (all threads compute identical result)
    float bv = pv[buf][0]; int bi = pi2[buf][0];
#pragma unroll
    for (int w = 1; w < 4; ++w) {
      float wv = pv[buf][w]; int wi = pi2[buf][w];
      if (wv > bv || (wv == bv && wi < bi)) { bv = wv; bi = wi; }
    }
    cx = sxyz[bi * 3 + 0]; cy = sxyz[bi * 3 + 1]; cz = sxyz[bi * 3 + 2];
    if (t == 0) { outb[it * 3 + 0] = cx; outb[it * 3 + 1] = cy; outb[it * 3 + 2] = cz; }
    buf ^= 1;
  }
}

// ---------------- MLP layer: X[32][Cin](LDS) x wT[Cin][Cout](global, float4) -> Y[32][Cout](LDS)
template <int CIN, int COUT, int XSTR, int YSTR>
__device__ __forceinline__ void mlp_layer(const float* Xb, const float* __restrict__ wT,
                                          const float* __restrict__ Aa, const float* __restrict__ Bb,
                                          float* Yb, int t) {
  constexpr int NJ = COUT / 8;
  const int og = t & 7, kk = t >> 3;
  const int obase = og * NJ;
  float acc[NJ];
#pragma unroll
  for (int j = 0; j < NJ; ++j) acc[j] = 0.f;
  const float* xrow = Xb + kk * XSTR;
  for (int c = 0; c < CIN; ++c) {
    float xv = xrow[c];
    const float4* wr4 = reinterpret_cast<const float4*>(wT + c * COUT + obase);
#pragma unroll
    for (int j4 = 0; j4 < NJ / 4; ++j4) {
      float4 wv = wr4[j4];
      acc[j4 * 4 + 0] = fmaf(xv, wv.x, acc[j4 * 4 + 0]);
      acc[j4 * 4 + 1] = fmaf(xv, wv.y, acc[j4 * 4 + 1]);
      acc[j4 * 4 + 2] = fmaf(xv, wv.z, acc[j4 * 4 + 2]);
      acc[j4 * 4 + 3] = fmaf(xv, wv.w, acc[j4 * 4 + 3]);
    }
  }
#pragma unroll
  for (int j = 0; j < NJ; ++j) {
    int o = obase + j;
    Yb[kk * YSTR + o] = fmaxf(fmaf(acc[j], Aa[o], Bb[o]), 0.f);  // BN(eval) + ReLU
  }
}

// ---------------- fused 32-NN + gather + MLP + maxpool: one block per (b,s) ----------------
__global__ __launch_bounds__(256) void knnmlp_kernel(
    const float* __restrict__ xyz, const float* __restrict__ points,
    const float* __restrict__ ws, const float* __restrict__ newxyz,
    float* __restrict__ outp) {
  const int blk = blockIdx.x;
  const int b = blk >> 10, s = blk & 1023;
  const int t = threadIdx.x;
  const float* xb = xyz + (size_t)b * NPTS * 3;
  const float* pb = points + (size_t)b * NPTS * CPTS;
  const float* q  = newxyz + ((size_t)b * NS + s) * 3;
  float qx = q[0], qy = q[1], qz = q[2];
  // exact replication of (s2 - 2*dot) + n2
  float s2 = __fadd_rn(__fadd_rn(__fmul_rn(qx, qx), __fmul_rn(qy, qy)), __fmul_rn(qz, qz));
  unsigned long long key[16];
#pragma unroll
  for (int j = 0; j < 16; ++j) {
    int n = t + 256 * j;
    float px = xb[n * 3], py = xb[n * 3 + 1], pz = xb[n * 3 + 2];
    float n2 = __fadd_rn(__fadd_rn(__fmul_rn(px, px), __fmul_rn(py, py)), __fmul_rn(pz, pz));
    float dt = __fadd_rn(__fadd_rn(__fmul_rn(qx, px), __fmul_rn(qy, py)), __fmul_rn(qz, pz));
    float d  = __fadd_rn(__fsub_rn(s2, __fmul_rn(2.0f, dt)), n2);
    // monotone float->uint map (handles tiny negative d from rounding)
    unsigned u = __float_as_uint(d);
    u ^= (0x80000000u | (unsigned)((int)u >> 31));
    key[j] = ((unsigned long long)u << 32) | (unsigned)n;
  }

  __shared__ unsigned long long wlist[128];
  __shared__ int nn[KNB];

  // per-wave top-32 (sorted ascending), zero barriers
  const int w = t >> 6;
  unsigned long long last = 0ull;
  for (int r = 0; r < KNB; ++r) {
    unsigned long long best = 0xFFFFFFFFFFFFFFFFull;
#pragma unroll
    for (int j = 0; j < 16; ++j) {
      if (key[j] > last && key[j] < best) best = key[j];
    }
#pragma unroll
    for (int off = 32; off >= 1; off >>= 1) {
      unsigned long long o = __shfl_xor(best, off, 64);
      if (o < best) best = o;
    }
    last = best;
    if ((t & 63) == 0) wlist[w * 32 + r] = best;
  }
  __syncthreads();

  // rank-merge: global rank of each of the 128 candidates (keys are unique)
  if (t < 128) {
    unsigned long long mykey = wlist[t];
    int gr = 0;
#pragma unroll 8
    for (int i = 0; i < 128; ++i) gr += (wlist[i] < mykey) ? 1 : 0;
    if (gr < KNB) nn[gr] = (int)(mykey & 0xFFFFFFFFull);
  }
  __syncthreads();

  __shared__ float X[32][68];
  __shared__ float P[32][68];
  __shared__ float O2[32][132];

  // gather grouped features: [32][3 xyz-norm | 64 point feats]
  for (int e = t; e < 32 * 67; e += 256) {
    int k = e / 67, c = e - k * 67;
    int idx = nn[k];
    float v;
    if (c < 3) {
      float qc = (c == 0) ? qx : ((c == 1) ? qy : qz);
      v = __fsub_rn(xb[idx * 3 + c], qc);
    } else {
      v = pb[idx * CPTS + (c - 3)];
    }
    X[k][c] = v;
  }
  __syncthreads();

  mlp_layer<67, 64, 68, 68>(&X[0][0], ws + WT0_OFF, ws + PRM_OFF, ws + PRM_OFF + 64, &P[0][0], t);
  __syncthreads();
  mlp_layer<64, 64, 68, 68>(&P[0][0], ws + WT1_OFF, ws + PRM_OFF + 128, ws + PRM_OFF + 192, &X[0][0], t);
  __syncthreads();
  mlp_layer<64, 128, 68, 132>(&X[0][0], ws + WT2_OFF, ws + PRM_OFF + 256, ws + PRM_OFF + 384, &O2[0][0], t);
  __syncthreads();

  if (t < 128) {
    float m = O2[0][t];
#pragma unroll
    for (int k2 = 1; k2 < 32; ++k2) m = fmaxf(m, O2[k2][t]);
    outp[((size_t)b * 128 + t) * NS + s] = m;
  }
}

extern "C" void kernel_launch(void* const* d_in, const int* in_sizes, int n_in,
                              void* d_out, int out_size, void* d_ws, size_t ws_size,
                              hipStream_t stream) {
  const float* xyz    = (const float*)d_in[0];
  const float* points = (const float*)d_in[1];
  const float* w0  = (const float*)d_in[2];
  const float* cb0 = (const float*)d_in[3];
  const float* g0  = (const float*)d_in[4];
  const float* b0  = (const float*)d_in[5];
  const float* m0  = (const float*)d_in[6];
  const float* v0  = (const float*)d_in[7];
  const float* w1  = (const float*)d_in[8];
  const float* cb1 = (const float*)d_in[9];
  const float* g1  = (const float*)d_in[10];
  const float* b1  = (const float*)d_in[11];
  const float* m1  = (const float*)d_in[12];
  const float* v1  = (const float*)d_in[13];
  const float* w2  = (const float*)d_in[14];
  const float* cb2 = (const float*)d_in[15];
  const float* g2  = (const float*)d_in[16];
  const float* b2  = (const float*)d_in[17];
  const float* m2  = (const float*)d_in[18];
  const float* v2  = (const float*)d_in[19];

  float* ws     = (float*)d_ws;
  float* newxyz = (float*)d_out;                       // output 0: [16,1024,3]
  float* outp   = (float*)d_out + (size_t)NB * NS * 3; // output 1: [16,128,1024]

  setup_kernel<<<(WS_FLOATS + 255) / 256, 256, 0, stream>>>(
      w0, cb0, g0, b0, m0, v0, w1, cb1, g1, b1, m1, v1, w2, cb2, g2, b2, m2, v2, ws);
  fps_kernel<<<NB, 256, 0, stream>>>(xyz, newxyz);
  knnmlp_kernel<<<NB * NS, 256, 0, stream>>>(xyz, points, ws, newxyz, outp);
}